// Round 14
// baseline (164.453 us; speedup 1.0000x reference)
//
#include <hip/hip_runtime.h>

typedef __attribute__((ext_vector_type(8))) short short8;
typedef __attribute__((ext_vector_type(4))) float f32x4;
typedef __attribute__((ext_vector_type(16))) float f32x16;

#define S_LEN 4096
#define C_DIM 512
#define NH 8
#define HD 64
#define NG 32
#define GS 16
#define LOG2E 1.44269504088896340736f

__device__ __forceinline__ unsigned short f2bf(float f) {
  union { float f; unsigned int u; } v; v.f = f;
  unsigned int r = v.u + 0x7fffu + ((v.u >> 16) & 1u);
  return (unsigned short)(r >> 16);
}

__device__ __forceinline__ float bf2f(unsigned short s) {
  union { unsigned u; float f; } v; v.u = (unsigned)s << 16;
  return v.f;
}

// raw v_exp_f32: computes 2^x, ~1 ulp; skips OCML denorm-range expansion.
__device__ __forceinline__ float fexp2(float x) {
  float r;
  asm("v_exp_f32 %0, %1" : "=v"(r) : "v"(x));
  return r;
}

__device__ __forceinline__ unsigned pk_bf16(float a, float b) {
  unsigned r;
  asm("v_cvt_pk_bf16_f32 %0, %1, %2" : "=v"(r) : "v"(a), "v"(b));
  return r;
}

// swap upper half of a with lower half of b (32-lane halves), both modified
__device__ __forceinline__ void pl_swap(unsigned& a, unsigned& b) {
  asm("v_permlane32_swap_b32 %0, %1" : "+v"(a), "+v"(b));
}
__device__ __forceinline__ void pl_swapf(float& a, float& b) {
  asm("v_permlane32_swap_b32 %0, %1" : "+v"(a), "+v"(b));
}

// async global->LDS, 16B per lane; LDS dest = wave-uniform base + lane*16
__device__ __forceinline__ void gload_lds16(const void* g, void* l) {
  __builtin_amdgcn_global_load_lds((const __attribute__((address_space(1))) void*)g,
                                   (__attribute__((address_space(3))) void*)l, 16, 0, 0);
}

// ---------------- fused prep: GroupNorm partial stats + both weight transposes ----------------
__global__ __launch_bounds__(256) void prep_kernel(const float* __restrict__ x,
                                                   float* __restrict__ partials,
                                                   const float* __restrict__ w_qkv,
                                                   unsigned short* __restrict__ wqkvT,
                                                   const float* __restrict__ w_proj,
                                                   unsigned short* __restrict__ wprojT) {
  __shared__ float tile[32][33];
  __shared__ float r1[4], r2[4];
  int bid = blockIdx.x;
  if (bid < 256) {
    int bg = bid >> 2, chunk = bid & 3;
    int b = bg >> 5, g = bg & 31;
    const float* xp = x + (size_t)b * S_LEN * C_DIM + g * GS;
    float s1 = 0.f, s2 = 0.f;
    for (int i = threadIdx.x; i < 1024 * 4; i += 256) {
      int s = chunk * 1024 + (i >> 2), c4 = i & 3;
      float4 v = *(const float4*)&xp[(size_t)s * C_DIM + c4 * 4];
      s1 += v.x + v.y + v.z + v.w;
      s2 += v.x * v.x + v.y * v.y + v.z * v.z + v.w * v.w;
    }
    for (int off = 1; off < 64; off <<= 1) {
      s1 += __shfl_xor(s1, off);
      s2 += __shfl_xor(s2, off);
    }
    int w = threadIdx.x >> 6;
    if ((threadIdx.x & 63) == 0) { r1[w] = s1; r2[w] = s2; }
    __syncthreads();
    if (threadIdx.x == 0) {
      partials[bg * 8 + chunk * 2]     = r1[0] + r1[1] + r1[2] + r1[3];
      partials[bg * 8 + chunk * 2 + 1] = r2[0] + r2[1] + r2[2] + r2[3];
    }
    return;
  }
  const float* src; unsigned short* dst; int K, N, n0, k0;
  if (bid < 1024) {
    int t = bid - 256;  src = w_qkv;  dst = wqkvT;  K = 512; N = 1536;
    n0 = (t % 48) * 32; k0 = (t / 48) * 32;
  } else {
    int t = bid - 1024; src = w_proj; dst = wprojT; K = 512; N = 512;
    n0 = (t % 16) * 32; k0 = (t / 16) * 32;
  }
  int c = threadIdx.x & 31, r0 = threadIdx.x >> 5;
  for (int i = 0; i < 4; ++i) {
    int r = r0 + i * 8;
    tile[r][c] = src[(size_t)(k0 + r) * N + n0 + c];
  }
  __syncthreads();
  for (int i = 0; i < 4; ++i) {
    int r = r0 + i * 8;
    dst[(size_t)(n0 + r) * K + k0 + c] = f2bf(tile[c][r]);
  }
}

// ---------------- fused QKV GEMM: GN-apply in A-staging + MFMA + head-split epilogue ----------
// A[m][c] = x[m][c]*As[c] + Cs[c] (GN refactored to one FMA; As=rstd*scale, Cs=bias-mean*As,
// per-block batch fixed). A reg-staged -> swizzled ds_write; B via gload_lds (pre-swz source).
__global__ __launch_bounds__(256) void gemm_qkv_kernel(const float* __restrict__ x,
                                                       const float* __restrict__ partials,
                                                       const float* __restrict__ gscale,
                                                       const float* __restrict__ gbias,
                                                       const unsigned short* __restrict__ Bt,  // [1536][512]
                                                       const float* __restrict__ qbias,
                                                       unsigned short* __restrict__ qh,
                                                       unsigned short* __restrict__ kh,
                                                       unsigned short* __restrict__ vh) {
  __shared__ unsigned char Alds[16384];   // [128 rows][128 B]
  __shared__ unsigned char Blds[16384];
  __shared__ float AsL[512], CsL[512];
  int tid = threadIdx.x, lane = tid & 63, w = tid >> 6;
  int li = lane & 15, g = lane >> 4;
  int wr = (w >> 1) * 64, wc = (w & 1) * 64;
  int m0 = blockIdx.y * 128, n0 = blockIdx.x * 128;
  int b_ = m0 >> 12;                    // tile fully inside one batch (128 | 4096)

  int srow = tid >> 3;
  int colS = (tid & 7) * 16;
  int sc   = colS ^ ((srow & 7) << 4);
  const char* bSrc = (const char*)Bt + (size_t)(n0 + srow) * 1024 + sc;

  // prologue: GN affine per channel
  const float invN = 1.0f / (float)(S_LEN * GS);
#pragma unroll
  for (int i = 0; i < 2; ++i) {
    int c = tid + i * 256;
    int bg = b_ * NG + (c >> 4);
    float s1 = partials[bg * 8] + partials[bg * 8 + 2] + partials[bg * 8 + 4] + partials[bg * 8 + 6];
    float s2 = partials[bg * 8 + 1] + partials[bg * 8 + 3] + partials[bg * 8 + 5] + partials[bg * 8 + 7];
    float mean = s1 * invN;
    float var = s2 * invN - mean * mean;
    float rstd = rsqrtf(var + 1e-6f);
    float A_ = rstd * gscale[c];
    AsL[c] = A_;
    CsL[c] = gbias[c] - mean * A_;
  }
  __syncthreads();

  // A staging geometry: row tr (0..127), col half hf2 (32 fp32 elems)
  int tr = tid >> 1, hf2 = tid & 1;
  const float* xRow = x + (size_t)(m0 + tr) * C_DIM + hf2 * 32;

  f32x4 acc[4][4];
  for (int i = 0; i < 4; ++i)
    for (int j = 0; j < 4; ++j) acc[i][j] = (f32x4){0.f, 0.f, 0.f, 0.f};

  for (int k0 = 0; k0 < 512; k0 += 64) {
    // x loads first (so their wait leaves B gloads in flight)
    float4 xv[8];
#pragma unroll
    for (int q = 0; q < 8; ++q) xv[q] = *(const float4*)&xRow[k0 + q * 4];
#pragma unroll
    for (int r = 0; r < 4; ++r)
      gload_lds16(bSrc + (size_t)r * 32 * 1024 + k0 * 2, &Blds[r * 4096 + tid * 16]);

    int cbase = k0 + hf2 * 32;
#pragma unroll
    for (int q = 0; q < 4; ++q) {
      union { unsigned u[4]; short8 v; } d;
#pragma unroll
      for (int p = 0; p < 2; ++p) {
        int c = cbase + q * 8 + p * 4;
        float4 A4 = *(const float4*)&AsL[c];
        float4 C4 = *(const float4*)&CsL[c];
        float4 vv = xv[2 * q + p];
        d.u[p * 2]     = pk_bf16(vv.x * A4.x + C4.x, vv.y * A4.y + C4.y);
        d.u[p * 2 + 1] = pk_bf16(vv.z * A4.z + C4.z, vv.w * A4.w + C4.w);
      }
      int cc = hf2 * 64 + q * 16;
      *(short8*)&Alds[tr * 128 + (cc ^ ((tr & 7) << 4))] = d.v;
    }
    __syncthreads();   // drains vmcnt (B gloads) + lgkm (A ds_writes)

#pragma unroll
    for (int ks = 0; ks < 2; ++ks) {
      short8 af[4], bfm[4];
#pragma unroll
      for (int mi = 0; mi < 4; ++mi) {
        int row = wr + mi * 16 + li;
        af[mi] = *(const short8*)&Alds[row * 128 + ((ks * 64 + g * 16) ^ ((row & 7) << 4))];
      }
#pragma unroll
      for (int ni = 0; ni < 4; ++ni) {
        int row = wc + ni * 16 + li;
        bfm[ni] = *(const short8*)&Blds[row * 128 + ((ks * 64 + g * 16) ^ ((row & 7) << 4))];
      }
#pragma unroll
      for (int mi = 0; mi < 4; ++mi)
#pragma unroll
        for (int ni = 0; ni < 4; ++ni)
          acc[mi][ni] = __builtin_amdgcn_mfma_f32_16x16x32_bf16(af[mi], bfm[ni], acc[mi][ni], 0, 0, 0);
    }
    __syncthreads();
  }

  for (int ni = 0; ni < 4; ++ni) {
    int n = n0 + wc + ni * 16 + li;
    float bn = qbias[n];
    int head = n / 192;
    int rem = n - head * 192;
    int part = rem >> 6;
    int h = rem & 63;
    if (part == 2) {
      for (int mi = 0; mi < 4; ++mi) {
        int m = m0 + wr + mi * 16 + g * 4;
        int b = m >> 12, s = m & 4095;
        size_t idx = ((size_t)(b * NH + head) * HD + h) * S_LEN + s;   // 4 consecutive s
        ushort4 val;
        val.x = f2bf(acc[mi][ni][0] + bn);
        val.y = f2bf(acc[mi][ni][1] + bn);
        val.z = f2bf(acc[mi][ni][2] + bn);
        val.w = f2bf(acc[mi][ni][3] + bn);
        *(ushort4*)&vh[idx] = val;
      }
    } else {
      unsigned short* dst = part == 0 ? qh : kh;
      float mul = part == 0 ? 0.125f * LOG2E : 1.0f;
      for (int mi = 0; mi < 4; ++mi)
        for (int j = 0; j < 4; ++j) {
          int m = m0 + wr + mi * 16 + g * 4 + j;
          int b = m >> 12, s = m & 4095;
          dst[((size_t)(b * NH + head) * S_LEN + s) * HD + h] = f2bf((acc[mi][ni][j] + bn) * mul);
        }
    }
  }
}

// ---------------- plain proj GEMM (fallback path): A [M][512] bf16 + bias + resid ----------------
__global__ __launch_bounds__(256) void gemm_plain_kernel(const unsigned short* __restrict__ A,
                                                         const unsigned short* __restrict__ Bt,
                                                         const float* __restrict__ bias,
                                                         const float* __restrict__ resid,
                                                         float* __restrict__ outf) {
  __shared__ unsigned char Alds[16384];
  __shared__ unsigned char Blds[16384];
  int tid = threadIdx.x, lane = tid & 63, w = tid >> 6;
  int li = lane & 15, g = lane >> 4;
  int wr = (w >> 1) * 64, wc = (w & 1) * 64;
  int m0 = blockIdx.y * 128, n0 = blockIdx.x * 128;

  int srow = tid >> 3;
  int colS = (tid & 7) * 16;
  int sc   = colS ^ ((srow & 7) << 4);
  const char* aSrc = (const char*)A + (size_t)(m0 + srow) * 1024 + sc;
  const char* bSrc = (const char*)Bt + (size_t)(n0 + srow) * 1024 + sc;

  f32x4 acc[4][4];
  for (int i = 0; i < 4; ++i)
    for (int j = 0; j < 4; ++j) acc[i][j] = (f32x4){0.f, 0.f, 0.f, 0.f};

  for (int k0 = 0; k0 < 512; k0 += 64) {
#pragma unroll
    for (int r = 0; r < 4; ++r) {
      gload_lds16(aSrc + (size_t)r * 32 * 1024 + k0 * 2, &Alds[r * 4096 + tid * 16]);
      gload_lds16(bSrc + (size_t)r * 32 * 1024 + k0 * 2, &Blds[r * 4096 + tid * 16]);
    }
    asm volatile("s_waitcnt vmcnt(0)" ::: "memory");
    __builtin_amdgcn_s_barrier();
#pragma unroll
    for (int ks = 0; ks < 2; ++ks) {
      short8 af[4], bfm[4];
#pragma unroll
      for (int mi = 0; mi < 4; ++mi) {
        int row = wr + mi * 16 + li;
        af[mi] = *(const short8*)&Alds[row * 128 + ((ks * 64 + g * 16) ^ ((row & 7) << 4))];
      }
#pragma unroll
      for (int ni = 0; ni < 4; ++ni) {
        int row = wc + ni * 16 + li;
        bfm[ni] = *(const short8*)&Blds[row * 128 + ((ks * 64 + g * 16) ^ ((row & 7) << 4))];
      }
#pragma unroll
      for (int mi = 0; mi < 4; ++mi)
#pragma unroll
        for (int ni = 0; ni < 4; ++ni)
          acc[mi][ni] = __builtin_amdgcn_mfma_f32_16x16x32_bf16(af[mi], bfm[ni], acc[mi][ni], 0, 0, 0);
    }
    __syncthreads();
  }

  for (int ni = 0; ni < 4; ++ni) {
    int n = n0 + wc + ni * 16 + li;
    float bn = bias[n];
    for (int mi = 0; mi < 4; ++mi)
      for (int j = 0; j < 4; ++j) {
        int m = m0 + wr + mi * 16 + g * 4 + j;
        size_t off = (size_t)m * C_DIM + n;
        outf[off] = acc[mi][ni][j] + bn + resid[off];
      }
  }
}

// ---------------- fused proj GEMM: combine(opart,lpart) -> A-tile -> MFMA -> +bias+resid ------
__global__ __launch_bounds__(256) void gemm_proj_kernel(const unsigned short* __restrict__ opart,
                                                        const float* __restrict__ lpart,
                                                        const unsigned short* __restrict__ Bt,  // [512][512]
                                                        const float* __restrict__ bias,
                                                        const float* __restrict__ resid,
                                                        float* __restrict__ outf) {
  __shared__ unsigned char Alds[16384];
  __shared__ unsigned char Blds[16384];
  __shared__ float linv[8][128];
  int tid = threadIdx.x, lane = tid & 63, w = tid >> 6;
  int li = lane & 15, g = lane >> 4;
  int wr = (w >> 1) * 64, wc = (w & 1) * 64;
  int m0 = blockIdx.y * 128, n0 = blockIdx.x * 128;
  int b_ = m0 >> 12;
  int s0 = m0 & 4095;

  int srow = tid >> 3;
  int colS = (tid & 7) * 16;
  int sc   = colS ^ ((srow & 7) << 4);
  const char* bSrc = (const char*)Bt + (size_t)(n0 + srow) * 1024 + sc;

#pragma unroll
  for (int i = 0; i < 4; ++i) {
    int e = tid + i * 256;
    int hd_ = e >> 7, r = e & 127;
    size_t rowA = (size_t)((b_ * NH + hd_) * 2) * S_LEN + s0 + r;
    linv[hd_][r] = 1.0f / (lpart[rowA] + lpart[rowA + S_LEN]);
  }
  __syncthreads();

  int tr = tid >> 1, hf2 = tid & 1;
  size_t rowBase = ((size_t)(b_ * NH) * 2) * S_LEN + s0 + tr;

  f32x4 acc[4][4];
  for (int i = 0; i < 4; ++i)
    for (int j = 0; j < 4; ++j) acc[i][j] = (f32x4){0.f, 0.f, 0.f, 0.f};

  for (int k0 = 0; k0 < 512; k0 += 64) {
    int head = k0 >> 6;
#pragma unroll
    for (int r = 0; r < 4; ++r)
      gload_lds16(bSrc + (size_t)r * 32 * 1024 + k0 * 2, &Blds[r * 4096 + tid * 16]);

    size_t rowA = rowBase + (size_t)head * 2 * S_LEN;
    const unsigned short* pA0 = opart + rowA * 64 + hf2 * 32;
    const unsigned short* pA1 = opart + (rowA + S_LEN) * 64 + hf2 * 32;
    float inv = linv[head][tr];
#pragma unroll
    for (int q = 0; q < 4; ++q) {
      short8 xx = *(const short8*)&pA0[q * 8];
      short8 yy = *(const short8*)&pA1[q * 8];
      union { unsigned u[4]; short8 v; } d;
#pragma unroll
      for (int p = 0; p < 4; ++p) {
        float f0 = (bf2f((unsigned short)xx[2 * p])     + bf2f((unsigned short)yy[2 * p]))     * inv;
        float f1 = (bf2f((unsigned short)xx[2 * p + 1]) + bf2f((unsigned short)yy[2 * p + 1])) * inv;
        d.u[p] = pk_bf16(f0, f1);
      }
      int cc = hf2 * 64 + q * 16;
      *(short8*)&Alds[tr * 128 + (cc ^ ((tr & 7) << 4))] = d.v;
    }
    __syncthreads();

#pragma unroll
    for (int ks = 0; ks < 2; ++ks) {
      short8 af[4], bfm[4];
#pragma unroll
      for (int mi = 0; mi < 4; ++mi) {
        int row = wr + mi * 16 + li;
        af[mi] = *(const short8*)&Alds[row * 128 + ((ks * 64 + g * 16) ^ ((row & 7) << 4))];
      }
#pragma unroll
      for (int ni = 0; ni < 4; ++ni) {
        int row = wc + ni * 16 + li;
        bfm[ni] = *(const short8*)&Blds[row * 128 + ((ks * 64 + g * 16) ^ ((row & 7) << 4))];
      }
#pragma unroll
      for (int mi = 0; mi < 4; ++mi)
#pragma unroll
        for (int ni = 0; ni < 4; ++ni)
          acc[mi][ni] = __builtin_amdgcn_mfma_f32_16x16x32_bf16(af[mi], bfm[ni], acc[mi][ni], 0, 0, 0);
    }
    __syncthreads();
  }

  for (int ni = 0; ni < 4; ++ni) {
    int n = n0 + wc + ni * 16 + li;
    float bn = bias[n];
    for (int mi = 0; mi < 4; ++mi)
      for (int j = 0; j < 4; ++j) {
        int m = m0 + wr + mi * 16 + g * 4 + j;
        size_t off = (size_t)m * C_DIM + n;
        outf[off] = acc[mi][ni][j] + bn + resid[off];
      }
  }
}

// ---------------- attention: 3-buffer counted-vmcnt ring, no-max softmax, l on VALU -----------
// l[q] = sum_t P: per-tile in-lane f32 tree-sum (15 adds), single cross-half permlane AFTER the
// loop (reduce commutes with accumulation). Frees 2 of 10 MFMAs/tile from the matrix pipe.
template <int SPLIT>
__global__ __launch_bounds__(256, 4) void attn_kernel(const unsigned short* __restrict__ qh,
                                                      const unsigned short* __restrict__ kh,
                                                      const unsigned short* __restrict__ vt,
                                                      unsigned short* __restrict__ ob,
                                                      unsigned short* __restrict__ opart,
                                                      float* __restrict__ lpart) {
  __shared__ unsigned char Kt[3 * 4096];
  __shared__ unsigned char Vt[3 * 4096];
  int bn = blockIdx.y;
  int half = SPLIT > 1 ? blockIdx.z : 0;
  int tid = threadIdx.x, lane = tid & 63, wv = tid >> 6;
  int r32 = lane & 31, hi_ = lane >> 5;
  int q0 = blockIdx.x * 128 + wv * 32;
  const int NT = S_LEN / 32 / SPLIT;
  const unsigned short* qp = qh + (size_t)bn * S_LEN * HD;
  const char* kp = (const char*)(kh + (size_t)bn * S_LEN * HD);
  const char* vp = (const char*)(vt + (size_t)bn * HD * S_LEN);

  int srow  = wv * 8 + (lane >> 3);
  int scolS = (lane & 7) * 16;
  int sc    = scolS ^ ((srow & 7) << 4);
  const char* kSrc = kp + (size_t)srow * 128 + sc + (size_t)half * (S_LEN / SPLIT) * 128;
  int vh_ = srow + ((sc >> 6) << 5);
  const char* vSrc = vp + (size_t)vh_ * (S_LEN * 2) + (sc & 63) + (size_t)half * (S_LEN / SPLIT) * 2;

  short8 qf[4];
#pragma unroll
  for (int ks = 0; ks < 4; ++ks)
    qf[ks] = *(const short8*)&qp[(size_t)(q0 + r32) * HD + ks * 16 + hi_ * 8];

  f32x16 o0, o1, z16;
#pragma unroll
  for (int i = 0; i < 16; ++i) { o0[i] = 0.f; o1[i] = 0.f; z16[i] = 0.f; }
  float lsum = 0.f;

  int swzr = (r32 & 7) << 4;
  int sBase = wv * 1024;

  gload_lds16(kSrc, &Kt[sBase]);
  gload_lds16(vSrc, &Vt[sBase]);
  gload_lds16(kSrc + 32 * 128, &Kt[4096 + sBase]);
  gload_lds16(vSrc + 32 * 2,   &Vt[4096 + sBase]);
  asm volatile("s_waitcnt vmcnt(2)" ::: "memory");
  __builtin_amdgcn_s_barrier();

  int curO = 0, nxtO = 4096, nnO = 8192;
  for (int it = 0; it < NT; ++it) {
    bool more = (it + 2 < NT);
    if (more) {
      size_t t0n = (size_t)(it + 2) * 32;
      gload_lds16(kSrc + t0n * 128, &Kt[nnO + sBase]);
      gload_lds16(vSrc + t0n * 2,   &Vt[nnO + sBase]);
    }

    const unsigned char* Kr = &Kt[curO + r32 * 128];
    const unsigned char* Vr = &Vt[curO + r32 * 128];
    short8 kf[4], vf[4];
#pragma unroll
    for (int ks = 0; ks < 4; ++ks)
      kf[ks] = *(const short8*)&Kr[(ks * 32 + hi_ * 16) ^ swzr];
#pragma unroll
    for (int kk = 0; kk < 2; ++kk)
#pragma unroll
      for (int hf = 0; hf < 2; ++hf)
        vf[kk * 2 + hf] = *(const short8*)&Vr[(hf * 64 + kk * 32 + hi_ * 16) ^ swzr];

    f32x16 s = __builtin_amdgcn_mfma_f32_32x32x16_bf16(kf[0], qf[0], z16, 0, 0, 0);
#pragma unroll
    for (int ks = 1; ks < 4; ++ks)
      s = __builtin_amdgcn_mfma_f32_32x32x16_bf16(kf[ks], qf[ks], s, 0, 0, 0);

#pragma unroll
    for (int i = 0; i < 16; ++i) s[i] = fexp2(s[i]);

    // l on VALU: in-lane tree sum (cross-half deferred to after the loop)
    float t0 = (s[0] + s[1]) + (s[2] + s[3]);
    float t1 = (s[4] + s[5]) + (s[6] + s[7]);
    float t2 = (s[8] + s[9]) + (s[10] + s[11]);
    float t3 = (s[12] + s[13]) + (s[14] + s[15]);
    lsum += (t0 + t1) + (t2 + t3);

    unsigned pkv[8];
#pragma unroll
    for (int g2 = 0; g2 < 8; ++g2) pkv[g2] = pk_bf16(s[2 * g2], s[2 * g2 + 1]);
    pl_swap(pkv[0], pkv[2]); pl_swap(pkv[1], pkv[3]);
    pl_swap(pkv[4], pkv[6]); pl_swap(pkv[5], pkv[7]);
    union { unsigned u[4]; short8 v; } F0, F1;
    F0.u[0] = pkv[0]; F0.u[1] = pkv[1]; F0.u[2] = pkv[2]; F0.u[3] = pkv[3];
    F1.u[0] = pkv[4]; F1.u[1] = pkv[5]; F1.u[2] = pkv[6]; F1.u[3] = pkv[7];

    o0 = __builtin_amdgcn_mfma_f32_32x32x16_bf16(vf[0], F0.v, o0, 0, 0, 0);
    o1 = __builtin_amdgcn_mfma_f32_32x32x16_bf16(vf[1], F0.v, o1, 0, 0, 0);
    o0 = __builtin_amdgcn_mfma_f32_32x32x16_bf16(vf[2], F1.v, o0, 0, 0, 0);
    o1 = __builtin_amdgcn_mfma_f32_32x32x16_bf16(vf[3], F1.v, o1, 0, 0, 0);

    if (more) asm volatile("s_waitcnt vmcnt(2)" ::: "memory");
    else      asm volatile("s_waitcnt vmcnt(0)" ::: "memory");
    __builtin_amdgcn_s_barrier();
    int t = curO; curO = nxtO; nxtO = nnO; nnO = t;
  }

  // cross-half reduce of l (once)
  { float c2 = lsum; pl_swapf(lsum, c2); lsum += c2; }

  if (SPLIT == 1) {
    float inv = 1.0f / lsum;
    int b = bn >> 3, n = bn & 7;
    size_t base = ((size_t)(b * S_LEN + q0 + r32)) * C_DIM + n * HD;
#pragma unroll
    for (int r = 0; r < 16; ++r) {
      int hrow = (r & 3) + 8 * (r >> 2) + 4 * hi_;
      ob[base + hrow]      = f2bf(o0[r] * inv);
      ob[base + 32 + hrow] = f2bf(o1[r] * inv);
    }
  } else {
    size_t row = (size_t)(bn * SPLIT + half) * S_LEN + q0 + r32;
    unsigned short* pp = opart + row * 64;
#pragma unroll
    for (int i = 0; i < 8; ++i) {
      int r = 2 * i;
      int hrow = (r & 3) + 8 * (r >> 2) + 4 * hi_;
      *(unsigned*)&pp[hrow]      = pk_bf16(o0[r], o0[r + 1]);
      *(unsigned*)&pp[32 + hrow] = pk_bf16(o1[r], o1[r + 1]);
    }
    if (!hi_) lpart[row] = lsum;
  }
}

extern "C" void kernel_launch(void* const* d_in, const int* in_sizes, int n_in,
                              void* d_out, int out_size, void* d_ws, size_t ws_size,
                              hipStream_t stream) {
  const float* x        = (const float*)d_in[0];
  const float* gn_scale = (const float*)d_in[1];
  const float* gn_bias  = (const float*)d_in[2];
  const float* w_qkv    = (const float*)d_in[3];
  const float* b_qkv    = (const float*)d_in[4];
  const float* w_proj   = (const float*)d_in[5];
  const float* b_proj   = (const float*)d_in[6];
  float* out = (float*)d_out;

  char* ws = (char*)d_ws;
  unsigned short* wqkvT  = (unsigned short*)(ws + 8388608);     //  1.5 MB [1536][512]
  unsigned short* wprojT = (unsigned short*)(ws + 9961472);     //  0.5 MB [512][512]
  unsigned short* qhb    = (unsigned short*)(ws + 10485760);    //  8 MB [B][NH][S][HD]
  unsigned short* khb    = (unsigned short*)(ws + 18874368);    //  8 MB [B][NH][S][HD]
  unsigned short* vtb    = (unsigned short*)(ws + 27262976);    //  8 MB [B][NH][HD][S]  (V^T)
  unsigned short* ahb    = (unsigned short*)(ws + 35651584);    //  8 MB [B*S][C]  (SPLIT=1 fallback)
  float* partials        = (float*)(ws + 44040192);             //  2 KB [64][4][2]
  float* lpart           = (float*)(ws + 44042240);             //  0.5 MB [16][2][4096] f32
  unsigned short* opart  = (unsigned short*)(ws + 45090816);    //  16.8 MB [16][2][4096][64] bf16
  const size_t NEED2 = 45090816ull + (size_t)16 * 2 * S_LEN * 64 * 2;   // ~61.9 MB

  prep_kernel<<<1280, 256, 0, stream>>>(x, partials, w_qkv, wqkvT, w_proj, wprojT);
  gemm_qkv_kernel<<<dim3(12, 64), 256, 0, stream>>>(x, partials, gn_scale, gn_bias, wqkvT, b_qkv,
                                                    qhb, khb, vtb);
  if (ws_size >= NEED2) {
    attn_kernel<2><<<dim3(32, 16, 2), 256, 0, stream>>>(qhb, khb, vtb, nullptr, opart, lpart);
    gemm_proj_kernel<<<dim3(4, 64), 256, 0, stream>>>(opart, lpart, wprojT, b_proj, x, out);
  } else {
    attn_kernel<1><<<dim3(32, 16, 1), 256, 0, stream>>>(qhb, khb, vtb, ahb, nullptr, nullptr);
    gemm_plain_kernel<<<dim3(4, 64), 256, 0, stream>>>(ahb, wprojT, b_proj, x, out);
  }
}

// Round 15
// 147.491 us; speedup vs baseline: 1.1150x; 1.1150x over previous
//
#include <hip/hip_runtime.h>

typedef __attribute__((ext_vector_type(8))) short short8;
typedef __attribute__((ext_vector_type(4))) float f32x4;
typedef __attribute__((ext_vector_type(16))) float f32x16;

#define S_LEN 4096
#define C_DIM 512
#define NH 8
#define HD 64
#define NG 32
#define GS 16
#define LOG2E 1.44269504088896340736f

__device__ __forceinline__ unsigned short f2bf(float f) {
  union { float f; unsigned int u; } v; v.f = f;
  unsigned int r = v.u + 0x7fffu + ((v.u >> 16) & 1u);
  return (unsigned short)(r >> 16);
}

__device__ __forceinline__ float bf2f(unsigned short s) {
  union { unsigned u; float f; } v; v.u = (unsigned)s << 16;
  return v.f;
}

// raw v_exp_f32: computes 2^x, ~1 ulp; skips OCML denorm-range expansion.
__device__ __forceinline__ float fexp2(float x) {
  float r;
  asm("v_exp_f32 %0, %1" : "=v"(r) : "v"(x));
  return r;
}

__device__ __forceinline__ unsigned pk_bf16(float a, float b) {
  unsigned r;
  asm("v_cvt_pk_bf16_f32 %0, %1, %2" : "=v"(r) : "v"(a), "v"(b));
  return r;
}

// swap upper half of a with lower half of b (32-lane halves), both modified
__device__ __forceinline__ void pl_swap(unsigned& a, unsigned& b) {
  asm("v_permlane32_swap_b32 %0, %1" : "+v"(a), "+v"(b));
}
__device__ __forceinline__ void pl_swapf(float& a, float& b) {
  asm("v_permlane32_swap_b32 %0, %1" : "+v"(a), "+v"(b));
}

// async global->LDS, 16B per lane; LDS dest = wave-uniform base + lane*16
__device__ __forceinline__ void gload_lds16(const void* g, void* l) {
  __builtin_amdgcn_global_load_lds((const __attribute__((address_space(1))) void*)g,
                                   (__attribute__((address_space(3))) void*)l, 16, 0, 0);
}

// ---------------- fused prep: GroupNorm partial stats + both weight transposes ----------------
__global__ __launch_bounds__(256) void prep_kernel(const float* __restrict__ x,
                                                   float* __restrict__ partials,
                                                   const float* __restrict__ w_qkv,
                                                   unsigned short* __restrict__ wqkvT,
                                                   const float* __restrict__ w_proj,
                                                   unsigned short* __restrict__ wprojT) {
  __shared__ float tile[32][33];
  __shared__ float r1[4], r2[4];
  int bid = blockIdx.x;
  if (bid < 256) {
    int bg = bid >> 2, chunk = bid & 3;
    int b = bg >> 5, g = bg & 31;
    const float* xp = x + (size_t)b * S_LEN * C_DIM + g * GS;
    float s1 = 0.f, s2 = 0.f;
    for (int i = threadIdx.x; i < 1024 * 4; i += 256) {
      int s = chunk * 1024 + (i >> 2), c4 = i & 3;
      float4 v = *(const float4*)&xp[(size_t)s * C_DIM + c4 * 4];
      s1 += v.x + v.y + v.z + v.w;
      s2 += v.x * v.x + v.y * v.y + v.z * v.z + v.w * v.w;
    }
    for (int off = 1; off < 64; off <<= 1) {
      s1 += __shfl_xor(s1, off);
      s2 += __shfl_xor(s2, off);
    }
    int w = threadIdx.x >> 6;
    if ((threadIdx.x & 63) == 0) { r1[w] = s1; r2[w] = s2; }
    __syncthreads();
    if (threadIdx.x == 0) {
      partials[bg * 8 + chunk * 2]     = r1[0] + r1[1] + r1[2] + r1[3];
      partials[bg * 8 + chunk * 2 + 1] = r2[0] + r2[1] + r2[2] + r2[3];
    }
    return;
  }
  const float* src; unsigned short* dst; int K, N, n0, k0;
  if (bid < 1024) {
    int t = bid - 256;  src = w_qkv;  dst = wqkvT;  K = 512; N = 1536;
    n0 = (t % 48) * 32; k0 = (t / 48) * 32;
  } else {
    int t = bid - 1024; src = w_proj; dst = wprojT; K = 512; N = 512;
    n0 = (t % 16) * 32; k0 = (t / 16) * 32;
  }
  int c = threadIdx.x & 31, r0 = threadIdx.x >> 5;
  for (int i = 0; i < 4; ++i) {
    int r = r0 + i * 8;
    tile[r][c] = src[(size_t)(k0 + r) * N + n0 + c];
  }
  __syncthreads();
  for (int i = 0; i < 4; ++i) {
    int r = r0 + i * 8;
    dst[(size_t)(n0 + r) * K + k0 + c] = f2bf(tile[c][r]);
  }
}

// ---------------- GroupNorm apply + bf16 cast (finalize from partials) ----------------
__global__ __launch_bounds__(256) void gn_apply_kernel(const float* __restrict__ x,
                                                       const float* __restrict__ partials,
                                                       const float* __restrict__ scale,
                                                       const float* __restrict__ bias,
                                                       unsigned short* __restrict__ out) {
  int idx = blockIdx.x * 256 + threadIdx.x;
  int e = idx * 4;
  int c = e & (C_DIM - 1);
  int bs = e >> 9;
  int b = bs >> 12;
  int grp = b * NG + (c >> 4);
  float s1 = partials[grp * 8] + partials[grp * 8 + 2] + partials[grp * 8 + 4] + partials[grp * 8 + 6];
  float s2 = partials[grp * 8 + 1] + partials[grp * 8 + 3] + partials[grp * 8 + 5] + partials[grp * 8 + 7];
  const float invN = 1.0f / (float)(S_LEN * GS);
  float mean = s1 * invN;
  float var = s2 * invN - mean * mean;
  float rstd = rsqrtf(var + 1e-6f);
  float4 v = *(const float4*)&x[e];
  ushort4 o;
  o.x = f2bf((v.x - mean) * rstd * scale[c]     + bias[c]);
  o.y = f2bf((v.y - mean) * rstd * scale[c + 1] + bias[c + 1]);
  o.z = f2bf((v.z - mean) * rstd * scale[c + 2] + bias[c + 2]);
  o.w = f2bf((v.w - mean) * rstd * scale[c + 3] + bias[c + 3]);
  *(ushort4*)&out[e] = o;
}

// ---------------- bf16 MFMA GEMM, 128x128 tile, global_load_lds staging + XOR swizzle ----------
// QKV epilogue: q scaled by (1/8)*log2e, K plain, V transposed with vectorized stores.
__global__ __launch_bounds__(256) void gemm_qkv_kernel(const unsigned short* __restrict__ A,   // [M][512]
                                                       const unsigned short* __restrict__ Bt,  // [1536][512]
                                                       const float* __restrict__ bias,
                                                       unsigned short* __restrict__ qh,
                                                       unsigned short* __restrict__ kh,
                                                       unsigned short* __restrict__ vh) {
  __shared__ unsigned char Alds[16384];   // [128 rows][128 B]
  __shared__ unsigned char Blds[16384];
  int tid = threadIdx.x, lane = tid & 63, w = tid >> 6;
  int li = lane & 15, g = lane >> 4;
  int wr = (w >> 1) * 64, wc = (w & 1) * 64;
  int m0 = blockIdx.y * 128, n0 = blockIdx.x * 128;

  int srow = tid >> 3;                 // 0..31
  int colS = (tid & 7) * 16;
  int sc   = colS ^ ((srow & 7) << 4);
  const char* aSrc = (const char*)A + (size_t)(m0 + srow) * 1024 + sc;
  const char* bSrc = (const char*)Bt + (size_t)(n0 + srow) * 1024 + sc;

  f32x4 acc[4][4];
  for (int i = 0; i < 4; ++i)
    for (int j = 0; j < 4; ++j) acc[i][j] = (f32x4){0.f, 0.f, 0.f, 0.f};

  for (int k0 = 0; k0 < 512; k0 += 64) {
#pragma unroll
    for (int r = 0; r < 4; ++r) {
      gload_lds16(aSrc + (size_t)r * 32 * 1024 + k0 * 2, &Alds[r * 4096 + tid * 16]);
      gload_lds16(bSrc + (size_t)r * 32 * 1024 + k0 * 2, &Blds[r * 4096 + tid * 16]);
    }
    asm volatile("s_waitcnt vmcnt(0)" ::: "memory");
    __builtin_amdgcn_s_barrier();

#pragma unroll
    for (int ks = 0; ks < 2; ++ks) {
      short8 af[4], bfm[4];
#pragma unroll
      for (int mi = 0; mi < 4; ++mi) {
        int row = wr + mi * 16 + li;
        af[mi] = *(const short8*)&Alds[row * 128 + ((ks * 64 + g * 16) ^ ((row & 7) << 4))];
      }
#pragma unroll
      for (int ni = 0; ni < 4; ++ni) {
        int row = wc + ni * 16 + li;
        bfm[ni] = *(const short8*)&Blds[row * 128 + ((ks * 64 + g * 16) ^ ((row & 7) << 4))];
      }
#pragma unroll
      for (int mi = 0; mi < 4; ++mi)
#pragma unroll
        for (int ni = 0; ni < 4; ++ni)
          acc[mi][ni] = __builtin_amdgcn_mfma_f32_16x16x32_bf16(af[mi], bfm[ni], acc[mi][ni], 0, 0, 0);
    }
    __syncthreads();
  }

  for (int ni = 0; ni < 4; ++ni) {
    int n = n0 + wc + ni * 16 + li;
    float bn = bias[n];
    int head = n / 192;
    int rem = n - head * 192;
    int part = rem >> 6;
    int h = rem & 63;
    if (part == 2) {
      for (int mi = 0; mi < 4; ++mi) {
        int m = m0 + wr + mi * 16 + g * 4;
        int b = m >> 12, s = m & 4095;
        size_t idx = ((size_t)(b * NH + head) * HD + h) * S_LEN + s;   // 4 consecutive s
        ushort4 val;
        val.x = f2bf(acc[mi][ni][0] + bn);
        val.y = f2bf(acc[mi][ni][1] + bn);
        val.z = f2bf(acc[mi][ni][2] + bn);
        val.w = f2bf(acc[mi][ni][3] + bn);
        *(ushort4*)&vh[idx] = val;
      }
    } else {
      unsigned short* dst = part == 0 ? qh : kh;
      float mul = part == 0 ? 0.125f * LOG2E : 1.0f;
      for (int mi = 0; mi < 4; ++mi)
        for (int j = 0; j < 4; ++j) {
          int m = m0 + wr + mi * 16 + g * 4 + j;
          int b = m >> 12, s = m & 4095;
          dst[((size_t)(b * NH + head) * S_LEN + s) * HD + h] = f2bf((acc[mi][ni][j] + bn) * mul);
        }
    }
  }
}

// ---------------- plain proj GEMM (fallback path): A [M][512] bf16 + bias + resid ----------------
__global__ __launch_bounds__(256) void gemm_plain_kernel(const unsigned short* __restrict__ A,
                                                         const unsigned short* __restrict__ Bt,
                                                         const float* __restrict__ bias,
                                                         const float* __restrict__ resid,
                                                         float* __restrict__ outf) {
  __shared__ unsigned char Alds[16384];
  __shared__ unsigned char Blds[16384];
  int tid = threadIdx.x, lane = tid & 63, w = tid >> 6;
  int li = lane & 15, g = lane >> 4;
  int wr = (w >> 1) * 64, wc = (w & 1) * 64;
  int m0 = blockIdx.y * 128, n0 = blockIdx.x * 128;

  int srow = tid >> 3;
  int colS = (tid & 7) * 16;
  int sc   = colS ^ ((srow & 7) << 4);
  const char* aSrc = (const char*)A + (size_t)(m0 + srow) * 1024 + sc;
  const char* bSrc = (const char*)Bt + (size_t)(n0 + srow) * 1024 + sc;

  f32x4 acc[4][4];
  for (int i = 0; i < 4; ++i)
    for (int j = 0; j < 4; ++j) acc[i][j] = (f32x4){0.f, 0.f, 0.f, 0.f};

  for (int k0 = 0; k0 < 512; k0 += 64) {
#pragma unroll
    for (int r = 0; r < 4; ++r) {
      gload_lds16(aSrc + (size_t)r * 32 * 1024 + k0 * 2, &Alds[r * 4096 + tid * 16]);
      gload_lds16(bSrc + (size_t)r * 32 * 1024 + k0 * 2, &Blds[r * 4096 + tid * 16]);
    }
    asm volatile("s_waitcnt vmcnt(0)" ::: "memory");
    __builtin_amdgcn_s_barrier();
#pragma unroll
    for (int ks = 0; ks < 2; ++ks) {
      short8 af[4], bfm[4];
#pragma unroll
      for (int mi = 0; mi < 4; ++mi) {
        int row = wr + mi * 16 + li;
        af[mi] = *(const short8*)&Alds[row * 128 + ((ks * 64 + g * 16) ^ ((row & 7) << 4))];
      }
#pragma unroll
      for (int ni = 0; ni < 4; ++ni) {
        int row = wc + ni * 16 + li;
        bfm[ni] = *(const short8*)&Blds[row * 128 + ((ks * 64 + g * 16) ^ ((row & 7) << 4))];
      }
#pragma unroll
      for (int mi = 0; mi < 4; ++mi)
#pragma unroll
        for (int ni = 0; ni < 4; ++ni)
          acc[mi][ni] = __builtin_amdgcn_mfma_f32_16x16x32_bf16(af[mi], bfm[ni], acc[mi][ni], 0, 0, 0);
    }
    __syncthreads();
  }

  for (int ni = 0; ni < 4; ++ni) {
    int n = n0 + wc + ni * 16 + li;
    float bn = bias[n];
    for (int mi = 0; mi < 4; ++mi)
      for (int j = 0; j < 4; ++j) {
        int m = m0 + wr + mi * 16 + g * 4 + j;
        size_t off = (size_t)m * C_DIM + n;
        outf[off] = acc[mi][ni][j] + bn + resid[off];
      }
  }
}

// ---------------- fused proj GEMM: combine(opart,lpart) -> A-tile -> MFMA -> +bias+resid ------
__global__ __launch_bounds__(256) void gemm_proj_kernel(const unsigned short* __restrict__ opart,
                                                        const float* __restrict__ lpart,
                                                        const unsigned short* __restrict__ Bt,  // [512][512]
                                                        const float* __restrict__ bias,
                                                        const float* __restrict__ resid,
                                                        float* __restrict__ outf) {
  __shared__ unsigned char Alds[16384];
  __shared__ unsigned char Blds[16384];
  __shared__ float linv[8][128];
  int tid = threadIdx.x, lane = tid & 63, w = tid >> 6;
  int li = lane & 15, g = lane >> 4;
  int wr = (w >> 1) * 64, wc = (w & 1) * 64;
  int m0 = blockIdx.y * 128, n0 = blockIdx.x * 128;
  int b_ = m0 >> 12;
  int s0 = m0 & 4095;

  int srow = tid >> 3;
  int colS = (tid & 7) * 16;
  int sc   = colS ^ ((srow & 7) << 4);
  const char* bSrc = (const char*)Bt + (size_t)(n0 + srow) * 1024 + sc;

#pragma unroll
  for (int i = 0; i < 4; ++i) {
    int e = tid + i * 256;
    int hd_ = e >> 7, r = e & 127;
    size_t rowA = (size_t)((b_ * NH + hd_) * 2) * S_LEN + s0 + r;
    linv[hd_][r] = 1.0f / (lpart[rowA] + lpart[rowA + S_LEN]);
  }
  __syncthreads();

  int tr = tid >> 1, hf2 = tid & 1;
  size_t rowBase = ((size_t)(b_ * NH) * 2) * S_LEN + s0 + tr;

  f32x4 acc[4][4];
  for (int i = 0; i < 4; ++i)
    for (int j = 0; j < 4; ++j) acc[i][j] = (f32x4){0.f, 0.f, 0.f, 0.f};

  for (int k0 = 0; k0 < 512; k0 += 64) {
    int head = k0 >> 6;
#pragma unroll
    for (int r = 0; r < 4; ++r)
      gload_lds16(bSrc + (size_t)r * 32 * 1024 + k0 * 2, &Blds[r * 4096 + tid * 16]);

    size_t rowA = rowBase + (size_t)head * 2 * S_LEN;
    const unsigned short* pA0 = opart + rowA * 64 + hf2 * 32;
    const unsigned short* pA1 = opart + (rowA + S_LEN) * 64 + hf2 * 32;
    float inv = linv[head][tr];
#pragma unroll
    for (int q = 0; q < 4; ++q) {
      short8 xx = *(const short8*)&pA0[q * 8];
      short8 yy = *(const short8*)&pA1[q * 8];
      union { unsigned u[4]; short8 v; } d;
#pragma unroll
      for (int p = 0; p < 4; ++p) {
        float f0 = (bf2f((unsigned short)xx[2 * p])     + bf2f((unsigned short)yy[2 * p]))     * inv;
        float f1 = (bf2f((unsigned short)xx[2 * p + 1]) + bf2f((unsigned short)yy[2 * p + 1])) * inv;
        d.u[p] = pk_bf16(f0, f1);
      }
      int cc = hf2 * 64 + q * 16;
      *(short8*)&Alds[tr * 128 + (cc ^ ((tr & 7) << 4))] = d.v;
    }
    __syncthreads();

#pragma unroll
    for (int ks = 0; ks < 2; ++ks) {
      short8 af[4], bfm[4];
#pragma unroll
      for (int mi = 0; mi < 4; ++mi) {
        int row = wr + mi * 16 + li;
        af[mi] = *(const short8*)&Alds[row * 128 + ((ks * 64 + g * 16) ^ ((row & 7) << 4))];
      }
#pragma unroll
      for (int ni = 0; ni < 4; ++ni) {
        int row = wc + ni * 16 + li;
        bfm[ni] = *(const short8*)&Blds[row * 128 + ((ks * 64 + g * 16) ^ ((row & 7) << 4))];
      }
#pragma unroll
      for (int mi = 0; mi < 4; ++mi)
#pragma unroll
        for (int ni = 0; ni < 4; ++ni)
          acc[mi][ni] = __builtin_amdgcn_mfma_f32_16x16x32_bf16(af[mi], bfm[ni], acc[mi][ni], 0, 0, 0);
    }
    __syncthreads();
  }

  for (int ni = 0; ni < 4; ++ni) {
    int n = n0 + wc + ni * 16 + li;
    float bn = bias[n];
    for (int mi = 0; mi < 4; ++mi)
      for (int j = 0; j < 4; ++j) {
        int m = m0 + wr + mi * 16 + g * 4 + j;
        size_t off = (size_t)m * C_DIM + n;
        outf[off] = acc[mi][ni][j] + bn + resid[off];
      }
  }
}

// ---------------- attention: 3-buffer counted-vmcnt ring, no-max softmax, l on VALU -----------
template <int SPLIT>
__global__ __launch_bounds__(256, 4) void attn_kernel(const unsigned short* __restrict__ qh,
                                                      const unsigned short* __restrict__ kh,
                                                      const unsigned short* __restrict__ vt,
                                                      unsigned short* __restrict__ ob,
                                                      unsigned short* __restrict__ opart,
                                                      float* __restrict__ lpart) {
  __shared__ unsigned char Kt[3 * 4096];
  __shared__ unsigned char Vt[3 * 4096];
  int bn = blockIdx.y;
  int half = SPLIT > 1 ? blockIdx.z : 0;
  int tid = threadIdx.x, lane = tid & 63, wv = tid >> 6;
  int r32 = lane & 31, hi_ = lane >> 5;
  int q0 = blockIdx.x * 128 + wv * 32;
  const int NT = S_LEN / 32 / SPLIT;
  const unsigned short* qp = qh + (size_t)bn * S_LEN * HD;
  const char* kp = (const char*)(kh + (size_t)bn * S_LEN * HD);
  const char* vp = (const char*)(vt + (size_t)bn * HD * S_LEN);

  int srow  = wv * 8 + (lane >> 3);
  int scolS = (lane & 7) * 16;
  int sc    = scolS ^ ((srow & 7) << 4);
  const char* kSrc = kp + (size_t)srow * 128 + sc + (size_t)half * (S_LEN / SPLIT) * 128;
  int vh_ = srow + ((sc >> 6) << 5);
  const char* vSrc = vp + (size_t)vh_ * (S_LEN * 2) + (sc & 63) + (size_t)half * (S_LEN / SPLIT) * 2;

  short8 qf[4];
#pragma unroll
  for (int ks = 0; ks < 4; ++ks)
    qf[ks] = *(const short8*)&qp[(size_t)(q0 + r32) * HD + ks * 16 + hi_ * 8];

  f32x16 o0, o1, z16;
#pragma unroll
  for (int i = 0; i < 16; ++i) { o0[i] = 0.f; o1[i] = 0.f; z16[i] = 0.f; }
  float lsum = 0.f;

  int swzr = (r32 & 7) << 4;
  int sBase = wv * 1024;

  gload_lds16(kSrc, &Kt[sBase]);
  gload_lds16(vSrc, &Vt[sBase]);
  gload_lds16(kSrc + 32 * 128, &Kt[4096 + sBase]);
  gload_lds16(vSrc + 32 * 2,   &Vt[4096 + sBase]);
  asm volatile("s_waitcnt vmcnt(2)" ::: "memory");
  __builtin_amdgcn_s_barrier();

  int curO = 0, nxtO = 4096, nnO = 8192;
  for (int it = 0; it < NT; ++it) {
    bool more = (it + 2 < NT);
    if (more) {
      size_t t0n = (size_t)(it + 2) * 32;
      gload_lds16(kSrc + t0n * 128, &Kt[nnO + sBase]);
      gload_lds16(vSrc + t0n * 2,   &Vt[nnO + sBase]);
    }

    const unsigned char* Kr = &Kt[curO + r32 * 128];
    const unsigned char* Vr = &Vt[curO + r32 * 128];
    short8 kf[4], vf[4];
#pragma unroll
    for (int ks = 0; ks < 4; ++ks)
      kf[ks] = *(const short8*)&Kr[(ks * 32 + hi_ * 16) ^ swzr];
#pragma unroll
    for (int kk = 0; kk < 2; ++kk)
#pragma unroll
      for (int hf = 0; hf < 2; ++hf)
        vf[kk * 2 + hf] = *(const short8*)&Vr[(hf * 64 + kk * 32 + hi_ * 16) ^ swzr];

    f32x16 s = __builtin_amdgcn_mfma_f32_32x32x16_bf16(kf[0], qf[0], z16, 0, 0, 0);
#pragma unroll
    for (int ks = 1; ks < 4; ++ks)
      s = __builtin_amdgcn_mfma_f32_32x32x16_bf16(kf[ks], qf[ks], s, 0, 0, 0);

#pragma unroll
    for (int i = 0; i < 16; ++i) s[i] = fexp2(s[i]);

    // l on VALU: in-lane tree sum (cross-half deferred to after the loop)
    float t0 = (s[0] + s[1]) + (s[2] + s[3]);
    float t1 = (s[4] + s[5]) + (s[6] + s[7]);
    float t2 = (s[8] + s[9]) + (s[10] + s[11]);
    float t3 = (s[12] + s[13]) + (s[14] + s[15]);
    lsum += (t0 + t1) + (t2 + t3);

    unsigned pkv[8];
#pragma unroll
    for (int g2 = 0; g2 < 8; ++g2) pkv[g2] = pk_bf16(s[2 * g2], s[2 * g2 + 1]);
    pl_swap(pkv[0], pkv[2]); pl_swap(pkv[1], pkv[3]);
    pl_swap(pkv[4], pkv[6]); pl_swap(pkv[5], pkv[7]);
    union { unsigned u[4]; short8 v; } F0, F1;
    F0.u[0] = pkv[0]; F0.u[1] = pkv[1]; F0.u[2] = pkv[2]; F0.u[3] = pkv[3];
    F1.u[0] = pkv[4]; F1.u[1] = pkv[5]; F1.u[2] = pkv[6]; F1.u[3] = pkv[7];

    o0 = __builtin_amdgcn_mfma_f32_32x32x16_bf16(vf[0], F0.v, o0, 0, 0, 0);
    o1 = __builtin_amdgcn_mfma_f32_32x32x16_bf16(vf[1], F0.v, o1, 0, 0, 0);
    o0 = __builtin_amdgcn_mfma_f32_32x32x16_bf16(vf[2], F1.v, o0, 0, 0, 0);
    o1 = __builtin_amdgcn_mfma_f32_32x32x16_bf16(vf[3], F1.v, o1, 0, 0, 0);

    if (more) asm volatile("s_waitcnt vmcnt(2)" ::: "memory");
    else      asm volatile("s_waitcnt vmcnt(0)" ::: "memory");
    __builtin_amdgcn_s_barrier();
    int t = curO; curO = nxtO; nxtO = nnO; nnO = t;
  }

  // cross-half reduce of l (once)
  { float c2 = lsum; pl_swapf(lsum, c2); lsum += c2; }

  if (SPLIT == 1) {
    float inv = 1.0f / lsum;
    int b = bn >> 3, n = bn & 7;
    size_t base = ((size_t)(b * S_LEN + q0 + r32)) * C_DIM + n * HD;
#pragma unroll
    for (int r = 0; r < 16; ++r) {
      int hrow = (r & 3) + 8 * (r >> 2) + 4 * hi_;
      ob[base + hrow]      = f2bf(o0[r] * inv);
      ob[base + 32 + hrow] = f2bf(o1[r] * inv);
    }
  } else {
    size_t row = (size_t)(bn * SPLIT + half) * S_LEN + q0 + r32;
    unsigned short* pp = opart + row * 64;
#pragma unroll
    for (int i = 0; i < 8; ++i) {
      int r = 2 * i;
      int hrow = (r & 3) + 8 * (r >> 2) + 4 * hi_;
      *(unsigned*)&pp[hrow]      = pk_bf16(o0[r], o0[r + 1]);
      *(unsigned*)&pp[32 + hrow] = pk_bf16(o1[r], o1[r + 1]);
    }
    if (!hi_) lpart[row] = lsum;
  }
}

extern "C" void kernel_launch(void* const* d_in, const int* in_sizes, int n_in,
                              void* d_out, int out_size, void* d_ws, size_t ws_size,
                              hipStream_t stream) {
  const float* x        = (const float*)d_in[0];
  const float* gn_scale = (const float*)d_in[1];
  const float* gn_bias  = (const float*)d_in[2];
  const float* w_qkv    = (const float*)d_in[3];
  const float* b_qkv    = (const float*)d_in[4];
  const float* w_proj   = (const float*)d_in[5];
  const float* b_proj   = (const float*)d_in[6];
  float* out = (float*)d_out;

  char* ws = (char*)d_ws;
  unsigned short* q_in   = (unsigned short*)(ws);               //  8 MB [B*S][C] bf16
  unsigned short* wqkvT  = (unsigned short*)(ws + 8388608);     //  1.5 MB [1536][512]
  unsigned short* wprojT = (unsigned short*)(ws + 9961472);     //  0.5 MB [512][512]
  unsigned short* qhb    = (unsigned short*)(ws + 10485760);    //  8 MB [B][NH][S][HD]
  unsigned short* khb    = (unsigned short*)(ws + 18874368);    //  8 MB [B][NH][S][HD]
  unsigned short* vtb    = (unsigned short*)(ws + 27262976);    //  8 MB [B][NH][HD][S]  (V^T)
  unsigned short* ahb    = (unsigned short*)(ws + 35651584);    //  8 MB [B*S][C]  (SPLIT=1 fallback)
  float* partials        = (float*)(ws + 44040192);             //  2 KB [64][4][2]
  float* lpart           = (float*)(ws + 44042240);             //  0.5 MB [16][2][4096] f32
  unsigned short* opart  = (unsigned short*)(ws + 45090816);    //  16.8 MB [16][2][4096][64] bf16
  const size_t NEED2 = 45090816ull + (size_t)16 * 2 * S_LEN * 64 * 2;   // ~61.9 MB

  prep_kernel<<<1280, 256, 0, stream>>>(x, partials, w_qkv, wqkvT, w_proj, wprojT);
  gn_apply_kernel<<<4096, 256, 0, stream>>>(x, partials, gn_scale, gn_bias, q_in);
  gemm_qkv_kernel<<<dim3(12, 64), 256, 0, stream>>>(q_in, wqkvT, b_qkv, qhb, khb, vtb);
  if (ws_size >= NEED2) {
    attn_kernel<2><<<dim3(32, 16, 2), 256, 0, stream>>>(qhb, khb, vtb, nullptr, opart, lpart);
    gemm_proj_kernel<<<dim3(4, 64), 256, 0, stream>>>(opart, lpart, wprojT, b_proj, x, out);
  } else {
    attn_kernel<1><<<dim3(32, 16, 1), 256, 0, stream>>>(qhb, khb, vtb, ahb, nullptr, nullptr);
    gemm_plain_kernel<<<dim3(4, 64), 256, 0, stream>>>(ahb, wprojT, b_proj, x, out);
  }
}

// Round 16
// 146.081 us; speedup vs baseline: 1.1258x; 1.0097x over previous
//
#include <hip/hip_runtime.h>

typedef __attribute__((ext_vector_type(8))) short short8;
typedef __attribute__((ext_vector_type(4))) float f32x4;
typedef __attribute__((ext_vector_type(16))) float f32x16;

#define S_LEN 4096
#define C_DIM 512
#define NH 8
#define HD 64
#define NG 32
#define GS 16
#define LOG2E 1.44269504088896340736f

__device__ __forceinline__ unsigned short f2bf(float f) {
  union { float f; unsigned int u; } v; v.f = f;
  unsigned int r = v.u + 0x7fffu + ((v.u >> 16) & 1u);
  return (unsigned short)(r >> 16);
}

__device__ __forceinline__ float bf2f(unsigned short s) {
  union { unsigned u; float f; } v; v.u = (unsigned)s << 16;
  return v.f;
}

// raw v_exp_f32: computes 2^x, ~1 ulp; skips OCML denorm-range expansion.
__device__ __forceinline__ float fexp2(float x) {
  float r;
  asm("v_exp_f32 %0, %1" : "=v"(r) : "v"(x));
  return r;
}

__device__ __forceinline__ unsigned pk_bf16(float a, float b) {
  unsigned r;
  asm("v_cvt_pk_bf16_f32 %0, %1, %2" : "=v"(r) : "v"(a), "v"(b));
  return r;
}

__device__ __forceinline__ void pl_swapf(float& a, float& b) {
  asm("v_permlane32_swap_b32 %0, %1" : "+v"(a), "+v"(b));
}

// async global->LDS, 16B per lane; LDS dest = wave-uniform base + lane*16
__device__ __forceinline__ void gload_lds16(const void* g, void* l) {
  __builtin_amdgcn_global_load_lds((const __attribute__((address_space(1))) void*)g,
                                   (__attribute__((address_space(3))) void*)l, 16, 0, 0);
}

// ---------------- fused prep: GroupNorm partial stats + both weight transposes ----------------
__global__ __launch_bounds__(256) void prep_kernel(const float* __restrict__ x,
                                                   float* __restrict__ partials,
                                                   const float* __restrict__ w_qkv,
                                                   unsigned short* __restrict__ wqkvT,
                                                   const float* __restrict__ w_proj,
                                                   unsigned short* __restrict__ wprojT) {
  __shared__ float tile[32][33];
  __shared__ float r1[4], r2[4];
  int bid = blockIdx.x;
  if (bid < 256) {
    int bg = bid >> 2, chunk = bid & 3;
    int b = bg >> 5, g = bg & 31;
    const float* xp = x + (size_t)b * S_LEN * C_DIM + g * GS;
    float s1 = 0.f, s2 = 0.f;
    for (int i = threadIdx.x; i < 1024 * 4; i += 256) {
      int s = chunk * 1024 + (i >> 2), c4 = i & 3;
      float4 v = *(const float4*)&xp[(size_t)s * C_DIM + c4 * 4];
      s1 += v.x + v.y + v.z + v.w;
      s2 += v.x * v.x + v.y * v.y + v.z * v.z + v.w * v.w;
    }
    for (int off = 1; off < 64; off <<= 1) {
      s1 += __shfl_xor(s1, off);
      s2 += __shfl_xor(s2, off);
    }
    int w = threadIdx.x >> 6;
    if ((threadIdx.x & 63) == 0) { r1[w] = s1; r2[w] = s2; }
    __syncthreads();
    if (threadIdx.x == 0) {
      partials[bg * 8 + chunk * 2]     = r1[0] + r1[1] + r1[2] + r1[3];
      partials[bg * 8 + chunk * 2 + 1] = r2[0] + r2[1] + r2[2] + r2[3];
    }
    return;
  }
  const float* src; unsigned short* dst; int K, N, n0, k0;
  if (bid < 1024) {
    int t = bid - 256;  src = w_qkv;  dst = wqkvT;  K = 512; N = 1536;
    n0 = (t % 48) * 32; k0 = (t / 48) * 32;
  } else {
    int t = bid - 1024; src = w_proj; dst = wprojT; K = 512; N = 512;
    n0 = (t % 16) * 32; k0 = (t / 16) * 32;
  }
  int c = threadIdx.x & 31, r0 = threadIdx.x >> 5;
  for (int i = 0; i < 4; ++i) {
    int r = r0 + i * 8;
    tile[r][c] = src[(size_t)(k0 + r) * N + n0 + c];
  }
  __syncthreads();
  for (int i = 0; i < 4; ++i) {
    int r = r0 + i * 8;
    dst[(size_t)(n0 + r) * K + k0 + c] = f2bf(tile[c][r]);
  }
}

// ---------------- GroupNorm apply + bf16 cast (finalize from partials) ----------------
__global__ __launch_bounds__(256) void gn_apply_kernel(const float* __restrict__ x,
                                                       const float* __restrict__ partials,
                                                       const float* __restrict__ scale,
                                                       const float* __restrict__ bias,
                                                       unsigned short* __restrict__ out) {
  int idx = blockIdx.x * 256 + threadIdx.x;
  int e = idx * 4;
  int c = e & (C_DIM - 1);
  int bs = e >> 9;
  int b = bs >> 12;
  int grp = b * NG + (c >> 4);
  float s1 = partials[grp * 8] + partials[grp * 8 + 2] + partials[grp * 8 + 4] + partials[grp * 8 + 6];
  float s2 = partials[grp * 8 + 1] + partials[grp * 8 + 3] + partials[grp * 8 + 5] + partials[grp * 8 + 7];
  const float invN = 1.0f / (float)(S_LEN * GS);
  float mean = s1 * invN;
  float var = s2 * invN - mean * mean;
  float rstd = rsqrtf(var + 1e-6f);
  float4 v = *(const float4*)&x[e];
  ushort4 o;
  o.x = f2bf((v.x - mean) * rstd * scale[c]     + bias[c]);
  o.y = f2bf((v.y - mean) * rstd * scale[c + 1] + bias[c + 1]);
  o.z = f2bf((v.z - mean) * rstd * scale[c + 2] + bias[c + 2]);
  o.w = f2bf((v.w - mean) * rstd * scale[c + 3] + bias[c + 3]);
  *(ushort4*)&out[e] = o;
}

// ---------------- bf16 MFMA GEMM, 128x128 tile, global_load_lds staging + XOR swizzle ----------
// QKV epilogue: q scaled by (1/8)*log2e, K plain, V transposed with vectorized stores.
__global__ __launch_bounds__(256) void gemm_qkv_kernel(const unsigned short* __restrict__ A,   // [M][512]
                                                       const unsigned short* __restrict__ Bt,  // [1536][512]
                                                       const float* __restrict__ bias,
                                                       unsigned short* __restrict__ qh,
                                                       unsigned short* __restrict__ kh,
                                                       unsigned short* __restrict__ vh) {
  __shared__ unsigned char Alds[16384];   // [128 rows][128 B]
  __shared__ unsigned char Blds[16384];
  int tid = threadIdx.x, lane = tid & 63, w = tid >> 6;
  int li = lane & 15, g = lane >> 4;
  int wr = (w >> 1) * 64, wc = (w & 1) * 64;
  int m0 = blockIdx.y * 128, n0 = blockIdx.x * 128;

  int srow = tid >> 3;                 // 0..31
  int colS = (tid & 7) * 16;
  int sc   = colS ^ ((srow & 7) << 4);
  const char* aSrc = (const char*)A + (size_t)(m0 + srow) * 1024 + sc;
  const char* bSrc = (const char*)Bt + (size_t)(n0 + srow) * 1024 + sc;

  f32x4 acc[4][4];
  for (int i = 0; i < 4; ++i)
    for (int j = 0; j < 4; ++j) acc[i][j] = (f32x4){0.f, 0.f, 0.f, 0.f};

  for (int k0 = 0; k0 < 512; k0 += 64) {
#pragma unroll
    for (int r = 0; r < 4; ++r) {
      gload_lds16(aSrc + (size_t)r * 32 * 1024 + k0 * 2, &Alds[r * 4096 + tid * 16]);
      gload_lds16(bSrc + (size_t)r * 32 * 1024 + k0 * 2, &Blds[r * 4096 + tid * 16]);
    }
    asm volatile("s_waitcnt vmcnt(0)" ::: "memory");
    __builtin_amdgcn_s_barrier();

#pragma unroll
    for (int ks = 0; ks < 2; ++ks) {
      short8 af[4], bfm[4];
#pragma unroll
      for (int mi = 0; mi < 4; ++mi) {
        int row = wr + mi * 16 + li;
        af[mi] = *(const short8*)&Alds[row * 128 + ((ks * 64 + g * 16) ^ ((row & 7) << 4))];
      }
#pragma unroll
      for (int ni = 0; ni < 4; ++ni) {
        int row = wc + ni * 16 + li;
        bfm[ni] = *(const short8*)&Blds[row * 128 + ((ks * 64 + g * 16) ^ ((row & 7) << 4))];
      }
#pragma unroll
      for (int mi = 0; mi < 4; ++mi)
#pragma unroll
        for (int ni = 0; ni < 4; ++ni)
          acc[mi][ni] = __builtin_amdgcn_mfma_f32_16x16x32_bf16(af[mi], bfm[ni], acc[mi][ni], 0, 0, 0);
    }
    __syncthreads();
  }

  for (int ni = 0; ni < 4; ++ni) {
    int n = n0 + wc + ni * 16 + li;
    float bn = bias[n];
    int head = n / 192;
    int rem = n - head * 192;
    int part = rem >> 6;
    int h = rem & 63;
    if (part == 2) {
      for (int mi = 0; mi < 4; ++mi) {
        int m = m0 + wr + mi * 16 + g * 4;
        int b = m >> 12, s = m & 4095;
        size_t idx = ((size_t)(b * NH + head) * HD + h) * S_LEN + s;   // 4 consecutive s
        ushort4 val;
        val.x = f2bf(acc[mi][ni][0] + bn);
        val.y = f2bf(acc[mi][ni][1] + bn);
        val.z = f2bf(acc[mi][ni][2] + bn);
        val.w = f2bf(acc[mi][ni][3] + bn);
        *(ushort4*)&vh[idx] = val;
      }
    } else {
      unsigned short* dst = part == 0 ? qh : kh;
      float mul = part == 0 ? 0.125f * LOG2E : 1.0f;
      for (int mi = 0; mi < 4; ++mi)
        for (int j = 0; j < 4; ++j) {
          int m = m0 + wr + mi * 16 + g * 4 + j;
          int b = m >> 12, s = m & 4095;
          dst[((size_t)(b * NH + head) * S_LEN + s) * HD + h] = f2bf((acc[mi][ni][j] + bn) * mul);
        }
    }
  }
}

// ---------------- plain proj GEMM (fallback path): A [M][512] bf16 + bias + resid ----------------
__global__ __launch_bounds__(256) void gemm_plain_kernel(const unsigned short* __restrict__ A,
                                                         const unsigned short* __restrict__ Bt,
                                                         const float* __restrict__ bias,
                                                         const float* __restrict__ resid,
                                                         float* __restrict__ outf) {
  __shared__ unsigned char Alds[16384];
  __shared__ unsigned char Blds[16384];
  int tid = threadIdx.x, lane = tid & 63, w = tid >> 6;
  int li = lane & 15, g = lane >> 4;
  int wr = (w >> 1) * 64, wc = (w & 1) * 64;
  int m0 = blockIdx.y * 128, n0 = blockIdx.x * 128;

  int srow = tid >> 3;
  int colS = (tid & 7) * 16;
  int sc   = colS ^ ((srow & 7) << 4);
  const char* aSrc = (const char*)A + (size_t)(m0 + srow) * 1024 + sc;
  const char* bSrc = (const char*)Bt + (size_t)(n0 + srow) * 1024 + sc;

  f32x4 acc[4][4];
  for (int i = 0; i < 4; ++i)
    for (int j = 0; j < 4; ++j) acc[i][j] = (f32x4){0.f, 0.f, 0.f, 0.f};

  for (int k0 = 0; k0 < 512; k0 += 64) {
#pragma unroll
    for (int r = 0; r < 4; ++r) {
      gload_lds16(aSrc + (size_t)r * 32 * 1024 + k0 * 2, &Alds[r * 4096 + tid * 16]);
      gload_lds16(bSrc + (size_t)r * 32 * 1024 + k0 * 2, &Blds[r * 4096 + tid * 16]);
    }
    asm volatile("s_waitcnt vmcnt(0)" ::: "memory");
    __builtin_amdgcn_s_barrier();
#pragma unroll
    for (int ks = 0; ks < 2; ++ks) {
      short8 af[4], bfm[4];
#pragma unroll
      for (int mi = 0; mi < 4; ++mi) {
        int row = wr + mi * 16 + li;
        af[mi] = *(const short8*)&Alds[row * 128 + ((ks * 64 + g * 16) ^ ((row & 7) << 4))];
      }
#pragma unroll
      for (int ni = 0; ni < 4; ++ni) {
        int row = wc + ni * 16 + li;
        bfm[ni] = *(const short8*)&Blds[row * 128 + ((ks * 64 + g * 16) ^ ((row & 7) << 4))];
      }
#pragma unroll
      for (int mi = 0; mi < 4; ++mi)
#pragma unroll
        for (int ni = 0; ni < 4; ++ni)
          acc[mi][ni] = __builtin_amdgcn_mfma_f32_16x16x32_bf16(af[mi], bfm[ni], acc[mi][ni], 0, 0, 0);
    }
    __syncthreads();
  }

  for (int ni = 0; ni < 4; ++ni) {
    int n = n0 + wc + ni * 16 + li;
    float bn = bias[n];
    for (int mi = 0; mi < 4; ++mi)
      for (int j = 0; j < 4; ++j) {
        int m = m0 + wr + mi * 16 + g * 4 + j;
        size_t off = (size_t)m * C_DIM + n;
        outf[off] = acc[mi][ni][j] + bn + resid[off];
      }
  }
}

// ---------------- fused proj GEMM: combine(opart,lpart) -> A-tile -> MFMA -> +bias+resid ------
__global__ __launch_bounds__(256) void gemm_proj_kernel(const unsigned short* __restrict__ opart,
                                                        const float* __restrict__ lpart,
                                                        const unsigned short* __restrict__ Bt,  // [512][512]
                                                        const float* __restrict__ bias,
                                                        const float* __restrict__ resid,
                                                        float* __restrict__ outf) {
  __shared__ unsigned char Alds[16384];
  __shared__ unsigned char Blds[16384];
  __shared__ float linv[8][128];
  int tid = threadIdx.x, lane = tid & 63, w = tid >> 6;
  int li = lane & 15, g = lane >> 4;
  int wr = (w >> 1) * 64, wc = (w & 1) * 64;
  int m0 = blockIdx.y * 128, n0 = blockIdx.x * 128;
  int b_ = m0 >> 12;
  int s0 = m0 & 4095;

  int srow = tid >> 3;
  int colS = (tid & 7) * 16;
  int sc   = colS ^ ((srow & 7) << 4);
  const char* bSrc = (const char*)Bt + (size_t)(n0 + srow) * 1024 + sc;

#pragma unroll
  for (int i = 0; i < 4; ++i) {
    int e = tid + i * 256;
    int hd_ = e >> 7, r = e & 127;
    size_t rowA = (size_t)((b_ * NH + hd_) * 2) * S_LEN + s0 + r;
    linv[hd_][r] = 1.0f / (lpart[rowA] + lpart[rowA + S_LEN]);
  }
  __syncthreads();

  int tr = tid >> 1, hf2 = tid & 1;
  size_t rowBase = ((size_t)(b_ * NH) * 2) * S_LEN + s0 + tr;

  f32x4 acc[4][4];
  for (int i = 0; i < 4; ++i)
    for (int j = 0; j < 4; ++j) acc[i][j] = (f32x4){0.f, 0.f, 0.f, 0.f};

  for (int k0 = 0; k0 < 512; k0 += 64) {
    int head = k0 >> 6;
#pragma unroll
    for (int r = 0; r < 4; ++r)
      gload_lds16(bSrc + (size_t)r * 32 * 1024 + k0 * 2, &Blds[r * 4096 + tid * 16]);

    size_t rowA = rowBase + (size_t)head * 2 * S_LEN;
    const unsigned short* pA0 = opart + rowA * 64 + hf2 * 32;
    const unsigned short* pA1 = opart + (rowA + S_LEN) * 64 + hf2 * 32;
    float inv = linv[head][tr];
#pragma unroll
    for (int q = 0; q < 4; ++q) {
      short8 xx = *(const short8*)&pA0[q * 8];
      short8 yy = *(const short8*)&pA1[q * 8];
      union { unsigned u[4]; short8 v; } d;
#pragma unroll
      for (int p = 0; p < 4; ++p) {
        float f0 = (bf2f((unsigned short)xx[2 * p])     + bf2f((unsigned short)yy[2 * p]))     * inv;
        float f1 = (bf2f((unsigned short)xx[2 * p + 1]) + bf2f((unsigned short)yy[2 * p + 1])) * inv;
        d.u[p] = pk_bf16(f0, f1);
      }
      int cc = hf2 * 64 + q * 16;
      *(short8*)&Alds[tr * 128 + (cc ^ ((tr & 7) << 4))] = d.v;
    }
    __syncthreads();

#pragma unroll
    for (int ks = 0; ks < 2; ++ks) {
      short8 af[4], bfm[4];
#pragma unroll
      for (int mi = 0; mi < 4; ++mi) {
        int row = wr + mi * 16 + li;
        af[mi] = *(const short8*)&Alds[row * 128 + ((ks * 64 + g * 16) ^ ((row & 7) << 4))];
      }
#pragma unroll
      for (int ni = 0; ni < 4; ++ni) {
        int row = wc + ni * 16 + li;
        bfm[ni] = *(const short8*)&Blds[row * 128 + ((ks * 64 + g * 16) ^ ((row & 7) << 4))];
      }
#pragma unroll
      for (int mi = 0; mi < 4; ++mi)
#pragma unroll
        for (int ni = 0; ni < 4; ++ni)
          acc[mi][ni] = __builtin_amdgcn_mfma_f32_16x16x32_bf16(af[mi], bfm[ni], acc[mi][ni], 0, 0, 0);
    }
    __syncthreads();
  }

  for (int ni = 0; ni < 4; ++ni) {
    int n = n0 + wc + ni * 16 + li;
    float bn = bias[n];
    for (int mi = 0; mi < 4; ++mi)
      for (int j = 0; j < 4; ++j) {
        int m = m0 + wr + mi * 16 + g * 4 + j;
        size_t off = (size_t)m * C_DIM + n;
        outf[off] = acc[mi][ni][j] + bn + resid[off];
      }
  }
}

// ---------------- attention: counted-vmcnt ring, no-max softmax, K-row-permuted P layout ------
// K loaded with row permutation pi(m)=(m&3)+4*(m>>3)+8*(m>>4)+8*((m>>2)&1): QK^T output
// row-slot m then holds P[t=pi(m)], so each lane's regs s[0..7]/s[8..15] ARE the PV
// B-fragments (k=8*hi+j) — no cross-lane exchange per tile. l on VALU, deferred cross-half.
template <int SPLIT>
__global__ __launch_bounds__(256, 4) void attn_kernel(const unsigned short* __restrict__ qh,
                                                      const unsigned short* __restrict__ kh,
                                                      const unsigned short* __restrict__ vt,
                                                      unsigned short* __restrict__ ob,
                                                      unsigned short* __restrict__ opart,
                                                      float* __restrict__ lpart) {
  __shared__ unsigned char Kt[3 * 4096];
  __shared__ unsigned char Vt[3 * 4096];
  int bn = blockIdx.y;
  int half = SPLIT > 1 ? blockIdx.z : 0;
  int tid = threadIdx.x, lane = tid & 63, wv = tid >> 6;
  int r32 = lane & 31, hi_ = lane >> 5;
  int q0 = blockIdx.x * 128 + wv * 32;
  const int NT = S_LEN / 32 / SPLIT;
  const unsigned short* qp = qh + (size_t)bn * S_LEN * HD;
  const char* kp = (const char*)(kh + (size_t)bn * S_LEN * HD);
  const char* vp = (const char*)(vt + (size_t)bn * HD * S_LEN);

  int srow  = wv * 8 + (lane >> 3);
  int scolS = (lane & 7) * 16;
  int sc    = scolS ^ ((srow & 7) << 4);
  const char* kSrc = kp + (size_t)srow * 128 + sc + (size_t)half * (S_LEN / SPLIT) * 128;
  int vh_ = srow + ((sc >> 6) << 5);
  const char* vSrc = vp + (size_t)vh_ * (S_LEN * 2) + (sc & 63) + (size_t)half * (S_LEN / SPLIT) * 2;

  short8 qf[4];
#pragma unroll
  for (int ks = 0; ks < 4; ++ks)
    qf[ks] = *(const short8*)&qp[(size_t)(q0 + r32) * HD + ks * 16 + hi_ * 8];

  f32x16 o0, o1, z16;
#pragma unroll
  for (int i = 0; i < 16; ++i) { o0[i] = 0.f; o1[i] = 0.f; z16[i] = 0.f; }
  float lsum = 0.f;

  // K-row permutation pi(r32): lane reads this K row as its A[m=r32] element
  int kRow = (r32 & 3) + 4 * (r32 >> 3) + 8 * (r32 >> 4) + 8 * ((r32 >> 2) & 1);
  int swzk = (kRow & 7) << 4;
  int swzr = (r32 & 7) << 4;
  int sBase = wv * 1024;

  gload_lds16(kSrc, &Kt[sBase]);
  gload_lds16(vSrc, &Vt[sBase]);
  gload_lds16(kSrc + 32 * 128, &Kt[4096 + sBase]);
  gload_lds16(vSrc + 32 * 2,   &Vt[4096 + sBase]);
  asm volatile("s_waitcnt vmcnt(2)" ::: "memory");
  __builtin_amdgcn_s_barrier();

  int curO = 0, nxtO = 4096, nnO = 8192;
  for (int it = 0; it < NT; ++it) {
    bool more = (it + 2 < NT);
    if (more) {
      size_t t0n = (size_t)(it + 2) * 32;
      gload_lds16(kSrc + t0n * 128, &Kt[nnO + sBase]);
      gload_lds16(vSrc + t0n * 2,   &Vt[nnO + sBase]);
    }

    const unsigned char* Kr = &Kt[curO + kRow * 128];
    const unsigned char* Vr = &Vt[curO + r32 * 128];
    short8 kf[4], vf[4];
#pragma unroll
    for (int ks = 0; ks < 4; ++ks)
      kf[ks] = *(const short8*)&Kr[(ks * 32 + hi_ * 16) ^ swzk];
#pragma unroll
    for (int kk = 0; kk < 2; ++kk)
#pragma unroll
      for (int hf = 0; hf < 2; ++hf)
        vf[kk * 2 + hf] = *(const short8*)&Vr[(hf * 64 + kk * 32 + hi_ * 16) ^ swzr];

    f32x16 s = __builtin_amdgcn_mfma_f32_32x32x16_bf16(kf[0], qf[0], z16, 0, 0, 0);
#pragma unroll
    for (int ks = 1; ks < 4; ++ks)
      s = __builtin_amdgcn_mfma_f32_32x32x16_bf16(kf[ks], qf[ks], s, 0, 0, 0);

#pragma unroll
    for (int i = 0; i < 16; ++i) s[i] = fexp2(s[i]);

    // l on VALU: in-lane tree sum (cross-half deferred to after the loop)
    float t0 = (s[0] + s[1]) + (s[2] + s[3]);
    float t1 = (s[4] + s[5]) + (s[6] + s[7]);
    float t2 = (s[8] + s[9]) + (s[10] + s[11]);
    float t3 = (s[12] + s[13]) + (s[14] + s[15]);
    lsum += (t0 + t1) + (t2 + t3);

    // PV B-fragments directly from s (K-row permutation made them lane-local)
    union { unsigned u[4]; short8 v; } F0, F1;
    F0.u[0] = pk_bf16(s[0], s[1]);   F0.u[1] = pk_bf16(s[2], s[3]);
    F0.u[2] = pk_bf16(s[4], s[5]);   F0.u[3] = pk_bf16(s[6], s[7]);
    F1.u[0] = pk_bf16(s[8], s[9]);   F1.u[1] = pk_bf16(s[10], s[11]);
    F1.u[2] = pk_bf16(s[12], s[13]); F1.u[3] = pk_bf16(s[14], s[15]);

    o0 = __builtin_amdgcn_mfma_f32_32x32x16_bf16(vf[0], F0.v, o0, 0, 0, 0);
    o1 = __builtin_amdgcn_mfma_f32_32x32x16_bf16(vf[1], F0.v, o1, 0, 0, 0);
    o0 = __builtin_amdgcn_mfma_f32_32x32x16_bf16(vf[2], F1.v, o0, 0, 0, 0);
    o1 = __builtin_amdgcn_mfma_f32_32x32x16_bf16(vf[3], F1.v, o1, 0, 0, 0);

    if (more) asm volatile("s_waitcnt vmcnt(2)" ::: "memory");
    else      asm volatile("s_waitcnt vmcnt(0)" ::: "memory");
    __builtin_amdgcn_s_barrier();
    int t = curO; curO = nxtO; nxtO = nnO; nnO = t;
  }

  // cross-half reduce of l (once)
  { float c2 = lsum; pl_swapf(lsum, c2); lsum += c2; }

  if (SPLIT == 1) {
    float inv = 1.0f / lsum;
    int b = bn >> 3, n = bn & 7;
    size_t base = ((size_t)(b * S_LEN + q0 + r32)) * C_DIM + n * HD;
#pragma unroll
    for (int r = 0; r < 16; ++r) {
      int hrow = (r & 3) + 8 * (r >> 2) + 4 * hi_;
      ob[base + hrow]      = f2bf(o0[r] * inv);
      ob[base + 32 + hrow] = f2bf(o1[r] * inv);
    }
  } else {
    size_t row = (size_t)(bn * SPLIT + half) * S_LEN + q0 + r32;
    unsigned short* pp = opart + row * 64;
#pragma unroll
    for (int i = 0; i < 8; ++i) {
      int r = 2 * i;
      int hrow = (r & 3) + 8 * (r >> 2) + 4 * hi_;   // even; hrow(r+1)=hrow+1
      *(unsigned*)&pp[hrow]      = pk_bf16(o0[r], o0[r + 1]);
      *(unsigned*)&pp[32 + hrow] = pk_bf16(o1[r], o1[r + 1]);
    }
    if (!hi_) lpart[row] = lsum;
  }
}

extern "C" void kernel_launch(void* const* d_in, const int* in_sizes, int n_in,
                              void* d_out, int out_size, void* d_ws, size_t ws_size,
                              hipStream_t stream) {
  const float* x        = (const float*)d_in[0];
  const float* gn_scale = (const float*)d_in[1];
  const float* gn_bias  = (const float*)d_in[2];
  const float* w_qkv    = (const float*)d_in[3];
  const float* b_qkv    = (const float*)d_in[4];
  const float* w_proj   = (const float*)d_in[5];
  const float* b_proj   = (const float*)d_in[6];
  float* out = (float*)d_out;

  char* ws = (char*)d_ws;
  unsigned short* q_in   = (unsigned short*)(ws);               //  8 MB [B*S][C] bf16
  unsigned short* wqkvT  = (unsigned short*)(ws + 8388608);     //  1.5 MB [1536][512]
  unsigned short* wprojT = (unsigned short*)(ws + 9961472);     //  0.5 MB [512][512]
  unsigned short* qhb    = (unsigned short*)(ws + 10485760);    //  8 MB [B][NH][S][HD]
  unsigned short* khb    = (unsigned short*)(ws + 18874368);    //  8 MB [B][NH][S][HD]
  unsigned short* vtb    = (unsigned short*)(ws + 27262976);    //  8 MB [B][NH][HD][S]  (V^T)
  unsigned short* ahb    = (unsigned short*)(ws + 35651584);    //  8 MB [B*S][C]  (SPLIT=1 fallback)
  float* partials        = (float*)(ws + 44040192);             //  2 KB [64][4][2]
  float* lpart           = (float*)(ws + 44042240);             //  0.5 MB [16][2][4096] f32
  unsigned short* opart  = (unsigned short*)(ws + 45090816);    //  16.8 MB [16][2][4096][64] bf16
  const size_t NEED2 = 45090816ull + (size_t)16 * 2 * S_LEN * 64 * 2;   // ~61.9 MB

  prep_kernel<<<1280, 256, 0, stream>>>(x, partials, w_qkv, wqkvT, w_proj, wprojT);
  gn_apply_kernel<<<4096, 256, 0, stream>>>(x, partials, gn_scale, gn_bias, q_in);
  gemm_qkv_kernel<<<dim3(12, 64), 256, 0, stream>>>(q_in, wqkvT, b_qkv, qhb, khb, vtb);
  if (ws_size >= NEED2) {
    attn_kernel<2><<<dim3(32, 16, 2), 256, 0, stream>>>(qhb, khb, vtb, nullptr, opart, lpart);
    gemm_proj_kernel<<<dim3(4, 64), 256, 0, stream>>>(opart, lpart, wprojT, b_proj, x, out);
  } else {
    attn_kernel<1><<<dim3(32, 16, 1), 256, 0, stream>>>(qhb, khb, vtb, ahb, nullptr, nullptr);
    gemm_plain_kernel<<<dim3(4, 64), 256, 0, stream>>>(ahb, wprojT, b_proj, x, out);
  }
}